// Round 3
// baseline (16433.217 us; speedup 1.0000x reference)
//
#include <hip/hip_runtime.h>
#include <hip/hip_fp16.h>

#define Bb 128
#define Tt 1024
#define Ii 256
#define Hh 512
#define Cc 10

#define HG   16
#define NBLK 64
#define COLS 32
#define LDP  520
#define LDPI 264

typedef _Float16 f16;
typedef _Float16 f16x8 __attribute__((ext_vector_type(8)));
typedef _Float16 f16x2 __attribute__((ext_vector_type(2)));
typedef float    f32x4 __attribute__((ext_vector_type(4)));

static __device__ __forceinline__ f32x4 mfma16(f16x8 a, f16x8 b, f32x4 c) {
  return __builtin_amdgcn_mfma_f32_16x16x32_f16(a, b, c, 0, 0, 0);
}
static __device__ __forceinline__ float fast_tanh(float v) {
  float e = __expf(2.0f * v);
  return 1.0f - 2.0f / (e + 1.0f);
}
// 16B coherent load (L2-bypassing, MALL-served); relaxed agent atomics coalesce per-wave
static __device__ __forceinline__ f16x8 ld16cc(const f16* p) {
  union { unsigned long long u[2]; f16x8 v; } U;
  U.u[0] = __hip_atomic_load((const unsigned long long*)p,     __ATOMIC_RELAXED, __HIP_MEMORY_SCOPE_AGENT);
  U.u[1] = __hip_atomic_load((const unsigned long long*)p + 1, __ATOMIC_RELAXED, __HIP_MEMORY_SCOPE_AGENT);
  return U.v;
}
static __device__ __forceinline__ void stu32cc(unsigned* p, unsigned v) {
  __hip_atomic_store(p, v, __ATOMIC_RELAXED, __HIP_MEMORY_SCOPE_AGENT);
}
static __device__ __forceinline__ int ldflag(const int* p) {
  return __hip_atomic_load(p, __ATOMIC_RELAXED, __HIP_MEMORY_SCOPE_AGENT);
}
static __device__ __forceinline__ void stflag(int* p, int v) {
  __hip_atomic_store(p, v, __ATOMIC_RELAXED, __HIP_MEMORY_SCOPE_AGENT);
}

__global__ __launch_bounds__(512, 1) void rnn_persistent(
    const float* __restrict__ x,
    const float* __restrict__ w_ih1, const float* __restrict__ w_hh1,
    const float* __restrict__ b_ih1, const float* __restrict__ b_hh1,
    const float* __restrict__ w_ih2, const float* __restrict__ w_hh2,
    const float* __restrict__ b_ih2, const float* __restrict__ b_hh2,
    const float* __restrict__ w_out, const float* __restrict__ b_out,
    float* __restrict__ out,
    int* __restrict__ f1, int* __restrict__ f2,
    f16* __restrict__ h1base, f16* __restrict__ h2base)
{
  __shared__ __align__(16) f16 ls_wih2[COLS][LDP];
  __shared__ __align__(16) f16 ls_whh2[COLS][LDP];
  __shared__ __align__(16) f16 ls_wih1[COLS][LDPI];

  const int hg   = blockIdx.x & (HG - 1);
  const int bg   = blockIdx.x >> 4;
  const int col0 = hg * COLS;
  const int row0 = bg * COLS;
  const int tid  = threadIdx.x;

  // ---- one-time LDS staging: w_ih2, w_hh2 (K=512), w_ih1 (K=256) ----
  for (int v = tid; v < COLS * (Hh / 4); v += 512) {
    const int j  = v >> 7;
    const int k4 = v & 127;
    const int gj = col0 + j;
    float4 a;
    a = ((const float4*)w_ih2)[gj * (Hh / 4) + k4];
    { f16 h0=(f16)a.x,h1_=(f16)a.y,h2_=(f16)a.z,h3=(f16)a.w;
      f16x2 p0{h0,h1_}, p1{h2_,h3};
      *(f16x2*)&ls_wih2[j][k4*4]   = p0; *(f16x2*)&ls_wih2[j][k4*4+2] = p1; }
    a = ((const float4*)w_hh2)[gj * (Hh / 4) + k4];
    { f16 h0=(f16)a.x,h1_=(f16)a.y,h2_=(f16)a.z,h3=(f16)a.w;
      f16x2 p0{h0,h1_}, p1{h2_,h3};
      *(f16x2*)&ls_whh2[j][k4*4]   = p0; *(f16x2*)&ls_whh2[j][k4*4+2] = p1; }
  }
  for (int v = tid; v < COLS * (Ii / 4); v += 512) {
    const int j  = v >> 6;
    const int k4 = v & 63;
    float4 a = ((const float4*)w_ih1)[(col0 + j) * (Ii / 4) + k4];
    f16 h0=(f16)a.x,h1_=(f16)a.y,h2_=(f16)a.z,h3=(f16)a.w;
    f16x2 p0{h0,h1_}, p1{h2_,h3};
    *(f16x2*)&ls_wih1[j][k4*4]   = p0; *(f16x2*)&ls_wih1[j][k4*4+2] = p1;
  }
  __syncthreads();

  // ---- wave geometry ----
  const int wid  = tid >> 6;           // 0..7
  const int lane = tid & 63;
  const bool isL1 = (wid < 4);
  const int wid2 = wid & 3;
  const int wr = wid2 >> 1, wc = wid2 & 1;
  const int lm  = lane & 15;
  const int lk8 = (lane >> 4) * 8;
  const int arow = row0 + wr * 16 + lm;      // A-frag batch row
  const int lcol = wc * 16 + lm;             // local B col
  const int gcol = col0 + lcol;              // global output col
  const int drow0 = row0 + wr * 16 + (lane >> 4) * 4;
  const int ce2 = gcol >> 1;
  const int rlo = (lane & 1) * 2;
  const size_t HB = (size_t)Bb * Hh;
  const int gw    = (bg * 2 + wr) * 32 + hg * 2 + wc;   // my flag slot
  const int pbase = (bg * 2 + wr) * 32;                 // my rows' 32 producers

  if (isL1) {
    // ---- whh1 B-fragments in registers (64 VGPR) ----
    f16x8 wb1[16];
    #pragma unroll
    for (int kc = 0; kc < 16; ++kc) {
      const float* wp = w_hh1 + (size_t)gcol * Hh + kc * 32 + lk8;
      float4 a = *(const float4*)wp, b = *(const float4*)(wp + 4);
      wb1[kc] = f16x8{(f16)a.x,(f16)a.y,(f16)a.z,(f16)a.w,
                      (f16)b.x,(f16)b.y,(f16)b.z,(f16)b.w};
    }
    const float bias1 = b_ih1[gcol] + b_hh1[gcol];

    // x-GEMM for timestep t -> f32x4 (2-way split accumulator)
    auto xgemm = [&](int t) -> f32x4 {
      const float* xr = x + (size_t)arow * (Tt * (size_t)Ii) + (size_t)t * Ii + lk8;
      float4 xa[8], xb[8];
      #pragma unroll
      for (int kc = 0; kc < 8; ++kc) {
        xa[kc] = *(const float4*)(xr + kc * 32);
        xb[kc] = *(const float4*)(xr + kc * 32 + 4);
      }
      f32x4 a0 = {0.f,0.f,0.f,0.f}, a1 = {0.f,0.f,0.f,0.f};
      #pragma unroll
      for (int kc = 0; kc < 8; kc += 2) {
        f16x8 fA{(f16)xa[kc].x,(f16)xa[kc].y,(f16)xa[kc].z,(f16)xa[kc].w,
                 (f16)xb[kc].x,(f16)xb[kc].y,(f16)xb[kc].z,(f16)xb[kc].w};
        a0 = mfma16(fA, *(const f16x8*)&ls_wih1[lcol][kc*32 + lk8], a0);
        f16x8 fB{(f16)xa[kc+1].x,(f16)xa[kc+1].y,(f16)xa[kc+1].z,(f16)xa[kc+1].w,
                 (f16)xb[kc+1].x,(f16)xb[kc+1].y,(f16)xb[kc+1].z,(f16)xb[kc+1].w};
        a1 = mfma16(fB, *(const f16x8*)&ls_wih1[lcol][(kc+1)*32 + lk8], a1);
      }
      return a0 + a1;
    };

    f32x4 xacc = xgemm(0);

    for (int p = 0; p < Tt; ++p) {
      f32x4 acc1a = xacc, acc1b = {0.f,0.f,0.f,0.f};
      if (p > 0) {
        // wait: h1_{p-1} published AND h2 engine done reading buffer (p&1)
        const int t1 = p, t2 = p - 1;
        int v1, v2;
        do {
          v1 = ldflag(f1 + pbase + (lane & 31));
          v2 = ldflag(f2 + pbase + (lane & 31));
        } while (!__all(v1 >= t1 && v2 >= t2));
        const f16* hr = h1base + (size_t)((p - 1) & 1) * HB + (size_t)arow * Hh + lk8;
        f16x8 ha[16];
        #pragma unroll
        for (int kc = 0; kc < 16; ++kc) ha[kc] = ld16cc(hr + kc * 32);
        #pragma unroll
        for (int kc = 0; kc < 16; kc += 2) {
          acc1a = mfma16(ha[kc],   wb1[kc],   acc1a);
          acc1b = mfma16(ha[kc+1], wb1[kc+1], acc1b);
        }
      }
      f32x4 acc1 = acc1a + acc1b;
      // tanh + pack col-pairs + coherent store
      {
        float v0 = fast_tanh(acc1[0]+bias1), v1 = fast_tanh(acc1[1]+bias1);
        float v2 = fast_tanh(acc1[2]+bias1), v3 = fast_tanh(acc1[3]+bias1);
        float o0=__shfl_xor(v0,1,64), o1=__shfl_xor(v1,1,64);
        float o2=__shfl_xor(v2,1,64), o3=__shfl_xor(v3,1,64);
        float m[4]={v0,v1,v2,v3}, q[4]={o0,o1,o2,o3};
        unsigned* b32 = (unsigned*)(h1base + (size_t)(p & 1) * HB);
        #pragma unroll
        for (int r = 0; r < 2; ++r) {
          int rr = rlo + r;
          float ve = (lane & 1) ? q[rr] : m[rr];
          float vo = (lane & 1) ? m[rr] : q[rr];
          union { f16x2 h; unsigned u; } P; P.h = f16x2{(f16)ve, (f16)vo};
          stu32cc(b32 + (size_t)(drow0 + rr) * (Hh/2) + ce2, P.u);
        }
      }
      asm volatile("s_waitcnt vmcnt(0)" ::: "memory");  // stores acked at MALL
      if (lane == 0) stflag(f1 + gw, p + 1);
      if (p + 1 < Tt) xacc = xgemm(p + 1);              // shadow work
    }
  } else {
    // ================= h2 engine =================
    const float bias2 = b_ih2[gcol] + b_hh2[gcol];
    for (int q = 0; q < Tt; ++q) {
      { // wait h1_q published
        const int t1 = q + 1; int v1;
        do { v1 = ldflag(f1 + pbase + (lane & 31)); } while (!__all(v1 >= t1));
      }
      const f16* hr1 = h1base + (size_t)(q & 1) * HB + (size_t)arow * Hh + lk8;
      f16x8 ha[16];
      #pragma unroll
      for (int kc = 0; kc < 16; ++kc) ha[kc] = ld16cc(hr1 + kc * 32);
      f32x4 a0 = {0.f,0.f,0.f,0.f}, a1 = {0.f,0.f,0.f,0.f};
      #pragma unroll
      for (int kc = 0; kc < 16; kc += 2) {
        a0 = mfma16(ha[kc],   *(const f16x8*)&ls_wih2[lcol][kc*32 + lk8],     a0);
        a1 = mfma16(ha[kc+1], *(const f16x8*)&ls_wih2[lcol][(kc+1)*32 + lk8], a1);
      }
      if (q > 0) { // wait h2_{q-1} published (also guards hb-buffer overwrite)
        int v2;
        do { v2 = ldflag(f2 + pbase + (lane & 31)); } while (!__all(v2 >= q));
      }
      const f16* hr2 = h2base + (size_t)((q - 1) & 1) * HB + (size_t)arow * Hh + lk8;
      f16x8 hb[16];
      #pragma unroll
      for (int kc = 0; kc < 16; ++kc) hb[kc] = ld16cc(hr2 + kc * 32);
      #pragma unroll
      for (int kc = 0; kc < 16; kc += 2) {
        a0 = mfma16(hb[kc],   *(const f16x8*)&ls_whh2[lcol][kc*32 + lk8],     a0);
        a1 = mfma16(hb[kc+1], *(const f16x8*)&ls_whh2[lcol][(kc+1)*32 + lk8], a1);
      }
      f32x4 acc2 = a0 + a1;
      {
        float v0 = fast_tanh(acc2[0]+bias2), v1 = fast_tanh(acc2[1]+bias2);
        float v2 = fast_tanh(acc2[2]+bias2), v3 = fast_tanh(acc2[3]+bias2);
        float o0=__shfl_xor(v0,1,64), o1=__shfl_xor(v1,1,64);
        float o2=__shfl_xor(v2,1,64), o3=__shfl_xor(v3,1,64);
        float m[4]={v0,v1,v2,v3}, qd[4]={o0,o1,o2,o3};
        unsigned* b32 = (unsigned*)(h2base + (size_t)(q & 1) * HB);
        #pragma unroll
        for (int r = 0; r < 2; ++r) {
          int rr = rlo + r;
          float ve = (lane & 1) ? qd[rr] : m[rr];
          float vo = (lane & 1) ? m[rr] : qd[rr];
          union { f16x2 h; unsigned u; } P; P.h = f16x2{(f16)ve, (f16)vo};
          stu32cc(b32 + (size_t)(drow0 + rr) * (Hh/2) + ce2, P.u);
        }
      }
      asm volatile("s_waitcnt vmcnt(0)" ::: "memory");
      if (lane == 0) stflag(f2 + gw, q + 1);
    }
  }

  // ---- final: out = h2_{T-1} @ w_out^T + b_out (buffer (T-1)&1 = 1) ----
  if (wid < 2) {
    const int row = blockIdx.x * 2 + wid;
    const int pb2 = ((row >> 5) * 2 + ((row >> 4) & 1)) * 32;
    int v;
    do { v = ldflag(f2 + pb2 + (lane & 31)); } while (!__all(v >= Tt));
    const f16* hrow = h2base + HB + (size_t)row * Hh + lane * 8;
    f16x8 hv = ld16cc(hrow);
    float hf[8];
    #pragma unroll
    for (int j = 0; j < 8; ++j) hf[j] = (float)hv[j];
    #pragma unroll
    for (int c = 0; c < Cc; ++c) {
      const float* wr_ = w_out + (size_t)c * Hh + lane * 8;
      float4 wa = *(const float4*)wr_;
      float4 wb = *(const float4*)(wr_ + 4);
      float s = hf[0]*wa.x + hf[1]*wa.y + hf[2]*wa.z + hf[3]*wa.w
              + hf[4]*wb.x + hf[5]*wb.y + hf[6]*wb.z + hf[7]*wb.w;
      #pragma unroll
      for (int off = 32; off >= 1; off >>= 1) s += __shfl_down(s, off, 64);
      if (lane == 0) out[row * Cc + c] = s + b_out[c];
    }
  }
}

extern "C" void kernel_launch(void* const* d_in, const int* in_sizes, int n_in,
                              void* d_out, int out_size, void* d_ws, size_t ws_size,
                              hipStream_t stream) {
  (void)in_sizes; (void)n_in; (void)out_size; (void)ws_size;
  const float* x     = (const float*)d_in[0];
  const float* w_ih1 = (const float*)d_in[1];
  const float* w_hh1 = (const float*)d_in[2];
  const float* b_ih1 = (const float*)d_in[3];
  const float* b_hh1 = (const float*)d_in[4];
  const float* w_ih2 = (const float*)d_in[5];
  const float* w_hh2 = (const float*)d_in[6];
  const float* b_ih2 = (const float*)d_in[7];
  const float* b_hh2 = (const float*)d_in[8];
  const float* w_out = (const float*)d_in[9];
  const float* b_out = (const float*)d_in[10];
  float* out = (float*)d_out;

  int* f1 = (int*)d_ws;                              // 256 ints (1KB)
  int* f2 = (int*)((char*)d_ws + 1024);              // 256 ints (1KB)
  _Float16* h1base = (_Float16*)((char*)d_ws + 4096);
  _Float16* h2base = h1base + 2 * (size_t)Bb * Hh;

  // zero flags + all four h ping-pong buffers (h_{-1} = 0)
  const size_t clear_bytes = 4096 + 4 * (size_t)Bb * Hh * sizeof(_Float16);
  hipMemsetAsync(d_ws, 0, clear_bytes, stream);

  hipLaunchKernelGGL(rnn_persistent, dim3(NBLK), dim3(512), 0, stream,
                     x, w_ih1, w_hh1, b_ih1, b_hh1,
                     w_ih2, w_hh2, b_ih2, b_hh2, w_out, b_out,
                     out, f1, f2, h1base, h2base);
}

// Round 5
// 16071.901 us; speedup vs baseline: 1.0225x; 1.0225x over previous
//
#include <hip/hip_runtime.h>
#include <hip/hip_fp16.h>

#define Bb 128
#define Tt 1024
#define Ii 256
#define Hh 512
#define Cc 10
#define NG 8            // batch groups (16 rows each)
#define RSLOT 4         // ring depth

typedef _Float16 f16;
typedef _Float16 f16x8 __attribute__((ext_vector_type(8)));
typedef _Float16 f16x2 __attribute__((ext_vector_type(2)));
typedef float    f32x4 __attribute__((ext_vector_type(4)));

// d_ws byte offsets
#define OFF_FLAGS 0u         // int[4][NG][8]
#define OFF_BIAS1 4096u      // f32[512]
#define OFF_BIAS2 8192u      // f32[512]
#define OFF_WIH1  16384u     // f16 [8][512][32]
#define OFF_WHH1  278528u    // f16 [16][512][32]
#define OFF_WIH2  802816u
#define OFF_WHH2  1327104u
#define OFF_XW1   1851392u   // f32 [4][NG][16][512]
#define OFF_H1R   2899968u   // f16 [4][NG][16][512]
#define OFF_PAR   3424256u   // f32 [4][NG][16][512]

static __device__ __forceinline__ f32x4 mfma16(f16x8 a, f16x8 b, f32x4 c) {
  return __builtin_amdgcn_mfma_f32_16x16x32_f16(a, b, c, 0, 0, 0);
}
static __device__ __forceinline__ float fast_tanh(float v) {
  float e = __expf(2.0f * v);
  return 1.0f - 2.0f / (e + 1.0f);
}
static __device__ __forceinline__ f16x8 ld16cc(const f16* p) {
  union { unsigned long long u[2]; f16x8 v; } U;
  U.u[0] = __hip_atomic_load((const unsigned long long*)p,     __ATOMIC_RELAXED, __HIP_MEMORY_SCOPE_AGENT);
  U.u[1] = __hip_atomic_load((const unsigned long long*)p + 1, __ATOMIC_RELAXED, __HIP_MEMORY_SCOPE_AGENT);
  return U.v;
}
static __device__ __forceinline__ float ldf32cc(const float* p) {
  unsigned u = __hip_atomic_load((const unsigned*)p, __ATOMIC_RELAXED, __HIP_MEMORY_SCOPE_AGENT);
  return __uint_as_float(u);
}
static __device__ __forceinline__ void stf32cc(float* p, float v) {
  __hip_atomic_store((unsigned*)p, __float_as_uint(v), __ATOMIC_RELAXED, __HIP_MEMORY_SCOPE_AGENT);
}
static __device__ __forceinline__ void stu32cc(unsigned* p, unsigned v) {
  __hip_atomic_store(p, v, __ATOMIC_RELAXED, __HIP_MEMORY_SCOPE_AGENT);
}
static __device__ __forceinline__ int ldflag(const int* p) {
  return __hip_atomic_load(p, __ATOMIC_RELAXED, __HIP_MEMORY_SCOPE_AGENT);
}
static __device__ __forceinline__ void stflag(int* p, int v) {
  __hip_atomic_store(p, v, __ATOMIC_RELAXED, __HIP_MEMORY_SCOPE_AGENT);
}

// ---------------- prologue: transpose+convert weights, fold biases ----------------
__global__ void prep_weights(const float* __restrict__ w_ih1, const float* __restrict__ w_hh1,
                             const float* __restrict__ w_ih2, const float* __restrict__ w_hh2,
                             const float* __restrict__ b_ih1, const float* __restrict__ b_hh1,
                             const float* __restrict__ b_ih2, const float* __restrict__ b_hh2,
                             char* __restrict__ ws) {
  f16* wt_ih1 = (f16*)(ws + OFF_WIH1);
  f16* wt_hh1 = (f16*)(ws + OFF_WHH1);
  f16* wt_ih2 = (f16*)(ws + OFF_WIH2);
  f16* wt_hh2 = (f16*)(ws + OFF_WHH2);
  float* bias1 = (float*)(ws + OFF_BIAS1);
  float* bias2 = (float*)(ws + OFF_BIAS2);
  int tid = blockIdx.x * 256 + threadIdx.x;
  if (tid < 512 * 512) {
    int c = tid >> 9, k = tid & 511;
    int kc = k >> 5, j = k & 31;
    size_t d = ((size_t)kc * 512 + c) * 32 + j;
    wt_hh1[d] = (f16)w_hh1[tid];
    wt_ih2[d] = (f16)w_ih2[tid];
    wt_hh2[d] = (f16)w_hh2[tid];
    if (k < 256) wt_ih1[d] = (f16)w_ih1[c * 256 + k];
    if (k == 0) { bias1[c] = b_ih1[c] + b_hh1[c]; bias2[c] = b_ih2[c] + b_hh2[c]; }
  }
}

// ---------------- main persistent pipeline ----------------
__global__ __launch_bounds__(512, 1) void rnn_pipeline(
    const float* __restrict__ x,
    const float* __restrict__ w_out, const float* __restrict__ b_out,
    float* __restrict__ out, char* __restrict__ ws)
{
  __shared__ __align__(16) f16 bC[4 * 512 * 32];   // 128 KB: kc 0..3 of this role's B
  __shared__ __align__(16) f16 hS[16 * 520];       // 16.6 KB h-state

  int* flags   = (int*)(ws + OFF_FLAGS);
  const float* bias1 = (const float*)(ws + OFF_BIAS1);
  const float* bias2 = (const float*)(ws + OFF_BIAS2);
  const f16* wt_ih1 = (const f16*)(ws + OFF_WIH1);
  const f16* wt_hh1 = (const f16*)(ws + OFF_WHH1);
  const f16* wt_ih2 = (const f16*)(ws + OFF_WIH2);
  const f16* wt_hh2 = (const f16*)(ws + OFF_WHH2);
  float* xw1 = (float*)(ws + OFF_XW1);
  f16*   h1r = (f16*)(ws + OFF_H1R);
  float* par = (float*)(ws + OFF_PAR);

  const int role = blockIdx.x & 3;   // 0=cell1 1=cell2a 2=cell2b 3=cell1x
  const int g    = blockIdx.x >> 2;
  const int row0 = g * 16;
  const int tid  = threadIdx.x;
  const int wid  = tid >> 6;
  const int lane = tid & 63;
  const int lm   = lane & 15;
  const int lk8  = (lane >> 4) * 8;
  const int drow = (lane >> 4) * 4;         // D rows drow..drow+3
  const int rlo  = (lane & 1) * 2;
  const int wcol0 = wid * 64;

  // ---- LDS B-cache: kc 0..3 of this role's streamed matrix ----
  {
    const f16* src = (role == 0) ? wt_hh1 : (role == 1) ? wt_ih2
                   : (role == 2) ? wt_hh2 : wt_ih1;
    for (int i = tid; i < 4 * 512 * 32 / 8; i += 512)
      ((f16x8*)bC)[i] = ((const f16x8*)src)[i];
  }
  if (role == 0 || role == 2) {
    for (int i = tid; i < 16 * 520 / 8; i += 512) ((f16x8*)hS)[i] = f16x8{0,0,0,0,0,0,0,0};
  }
  __syncthreads();

  auto waitge = [&](int role_, int tgt) {
    if (tgt <= 0) return;
    const int* fp = flags + (role_ * NG + g) * 8 + (lane & 7);
    int v; bool ok;
    do {
      v = ldflag(fp);
      ok = __all(v >= tgt);
      if (!ok) __builtin_amdgcn_s_sleep(1);
    } while (!ok);
  };
  auto bfrag = [&](const f16* mat, int kc, int nt) -> f16x8 {
    const int col = wcol0 + nt * 16 + lm;
    if (kc < 4) return *(const f16x8*)&bC[((size_t)(kc * 512) + col) * 32 + lk8];
    return *(const f16x8*)(mat + ((size_t)(kc * 512) + col) * 32 + lk8);
  };

  if (role == 3) {
    // ================= cell1x: xw1_s = x_s @ w_ih1^T + bias1 =================
    float b1v[4];
    #pragma unroll
    for (int nt = 0; nt < 4; ++nt) b1v[nt] = bias1[wcol0 + nt * 16 + lm];
    for (int s = 0; s < Tt; ++s) {
      waitge(0, s - (RSLOT - 1));
      const float* xr = x + (size_t)(row0 + lm) * (Tt * (size_t)Ii) + (size_t)s * Ii + lk8;
      f32x4 acc[4];
      #pragma unroll
      for (int nt = 0; nt < 4; ++nt) acc[nt] = f32x4{b1v[nt], b1v[nt], b1v[nt], b1v[nt]};
      #pragma unroll
      for (int kc = 0; kc < 8; ++kc) {
        float4 a0 = *(const float4*)(xr + kc * 32);
        float4 a1 = *(const float4*)(xr + kc * 32 + 4);
        f16x8 a{(f16)a0.x,(f16)a0.y,(f16)a0.z,(f16)a0.w,(f16)a1.x,(f16)a1.y,(f16)a1.z,(f16)a1.w};
        #pragma unroll
        for (int nt = 0; nt < 4; ++nt) acc[nt] = mfma16(a, bfrag(wt_ih1, kc, nt), acc[nt]);
      }
      float* dst = xw1 + ((size_t)(s & (RSLOT - 1)) * NG + g) * 16 * 512;
      #pragma unroll
      for (int nt = 0; nt < 4; ++nt) {
        const int dc = wcol0 + nt * 16 + lm;
        #pragma unroll
        for (int r = 0; r < 4; ++r) stf32cc(dst + (size_t)(drow + r) * 512 + dc, acc[nt][r]);
      }
      asm volatile("s_waitcnt vmcnt(0)" ::: "memory");
      if (lane == 0) stflag(flags + (3 * NG + g) * 8 + wid, s + 1);
    }
  } else if (role == 0) {
    // ================= cell1: h1 = tanh(xw1 + h1 @ w_hh1^T) =================
    for (int p = 0; p < Tt; ++p) {
      waitge(3, p + 1);
      waitge(1, p - (RSLOT - 1));
      const float* xw = xw1 + ((size_t)(p & (RSLOT - 1)) * NG + g) * 16 * 512;
      f32x4 acc[4];
      #pragma unroll
      for (int nt = 0; nt < 4; ++nt) {
        const int dc = wcol0 + nt * 16 + lm;
        #pragma unroll
        for (int r = 0; r < 4; ++r) acc[nt][r] = ldf32cc(xw + (size_t)(drow + r) * 512 + dc);
      }
      f16x8 A[16];
      if (p > 0) {
        #pragma unroll
        for (int kc = 0; kc < 16; ++kc) A[kc] = *(const f16x8*)&hS[lm * 520 + kc * 32 + lk8];
      }
      __syncthreads();   // reads of hS complete before overwrite
      if (p > 0) {
        #pragma unroll
        for (int kc = 0; kc < 16; ++kc) {
          #pragma unroll
          for (int nt = 0; nt < 4; ++nt) acc[nt] = mfma16(A[kc], bfrag(wt_hh1, kc, nt), acc[nt]);
        }
      }
      unsigned* ring32 = (unsigned*)(h1r + ((size_t)(p & (RSLOT - 1)) * NG + g) * 16 * 512);
      unsigned* hS32 = (unsigned*)hS;
      #pragma unroll
      for (int nt = 0; nt < 4; ++nt) {
        const int cp = (wcol0 + nt * 16 + lm) >> 1;
        float v0 = fast_tanh(acc[nt][0]), v1 = fast_tanh(acc[nt][1]);
        float v2 = fast_tanh(acc[nt][2]), v3 = fast_tanh(acc[nt][3]);
        float o0 = __shfl_xor(v0,1,64), o1 = __shfl_xor(v1,1,64);
        float o2 = __shfl_xor(v2,1,64), o3 = __shfl_xor(v3,1,64);
        float m[4] = {v0,v1,v2,v3}, q[4] = {o0,o1,o2,o3};
        #pragma unroll
        for (int r2 = 0; r2 < 2; ++r2) {
          const int rr = rlo + r2, row = drow + rr;
          float ve = (lane & 1) ? q[rr] : m[rr];
          float vo = (lane & 1) ? m[rr] : q[rr];
          union { f16x2 h; unsigned u; } P; P.h = f16x2{(f16)ve, (f16)vo};
          hS32[row * 260 + cp] = P.u;
          stu32cc(ring32 + row * 256 + cp, P.u);
        }
      }
      __syncthreads();   // waits lgkm+vm: hS visible, ring stores drained
      if (lane == 0) stflag(flags + (0 * NG + g) * 8 + wid, p + 1);
    }
  } else if (role == 1) {
    // ================= cell2a: partial = h1 @ w_ih2^T + bias2 =================
    float b2v[4];
    #pragma unroll
    for (int nt = 0; nt < 4; ++nt) b2v[nt] = bias2[wcol0 + nt * 16 + lm];
    for (int q = 0; q < Tt; ++q) {
      waitge(0, q + 1);
      waitge(2, q - (RSLOT - 1));
      const f16* h1s = h1r + ((size_t)(q & (RSLOT - 1)) * NG + g) * 16 * 512;
      f16x8 A[16];
      #pragma unroll
      for (int kc = 0; kc < 16; ++kc) A[kc] = ld16cc(h1s + (size_t)lm * 512 + kc * 32 + lk8);
      f32x4 acc[4];
      #pragma unroll
      for (int nt = 0; nt < 4; ++nt) acc[nt] = f32x4{b2v[nt], b2v[nt], b2v[nt], b2v[nt]};
      #pragma unroll
      for (int kc = 0; kc < 16; ++kc) {
        #pragma unroll
        for (int nt = 0; nt < 4; ++nt) acc[nt] = mfma16(A[kc], bfrag(wt_ih2, kc, nt), acc[nt]);
      }
      float* dst = par + ((size_t)(q & (RSLOT - 1)) * NG + g) * 16 * 512;
      #pragma unroll
      for (int nt = 0; nt < 4; ++nt) {
        const int dc = wcol0 + nt * 16 + lm;
        #pragma unroll
        for (int r = 0; r < 4; ++r) stf32cc(dst + (size_t)(drow + r) * 512 + dc, acc[nt][r]);
      }
      asm volatile("s_waitcnt vmcnt(0)" ::: "memory");
      if (lane == 0) stflag(flags + (1 * NG + g) * 8 + wid, q + 1);
    }
  } else {
    // ================= cell2b: h2 = tanh(partial + h2 @ w_hh2^T) =================
    for (int q = 0; q < Tt; ++q) {
      waitge(1, q + 1);
      const float* ps = par + ((size_t)(q & (RSLOT - 1)) * NG + g) * 16 * 512;
      f32x4 acc[4];
      #pragma unroll
      for (int nt = 0; nt < 4; ++nt) {
        const int dc = wcol0 + nt * 16 + lm;
        #pragma unroll
        for (int r = 0; r < 4; ++r) acc[nt][r] = ldf32cc(ps + (size_t)(drow + r) * 512 + dc);
      }
      f16x8 A[16];
      if (q > 0) {
        #pragma unroll
        for (int kc = 0; kc < 16; ++kc) A[kc] = *(const f16x8*)&hS[lm * 520 + kc * 32 + lk8];
      }
      __syncthreads();   // waits vm (partial loads) + lgkm (hS reads)
      if (lane == 0) stflag(flags + (2 * NG + g) * 8 + wid, q + 1);  // partial slot consumed
      if (q > 0) {
        #pragma unroll
        for (int kc = 0; kc < 16; ++kc) {
          #pragma unroll
          for (int nt = 0; nt < 4; ++nt) acc[nt] = mfma16(A[kc], bfrag(wt_hh2, kc, nt), acc[nt]);
        }
      }
      unsigned* hS32 = (unsigned*)hS;
      #pragma unroll
      for (int nt = 0; nt < 4; ++nt) {
        const int cp = (wcol0 + nt * 16 + lm) >> 1;
        float v0 = fast_tanh(acc[nt][0]), v1 = fast_tanh(acc[nt][1]);
        float v2 = fast_tanh(acc[nt][2]), v3 = fast_tanh(acc[nt][3]);
        float o0 = __shfl_xor(v0,1,64), o1 = __shfl_xor(v1,1,64);
        float o2 = __shfl_xor(v2,1,64), o3 = __shfl_xor(v3,1,64);
        float m[4] = {v0,v1,v2,v3}, qd[4] = {o0,o1,o2,o3};
        #pragma unroll
        for (int r2 = 0; r2 < 2; ++r2) {
          const int rr = rlo + r2, row = drow + rr;
          float ve = (lane & 1) ? qd[rr] : m[rr];
          float vo = (lane & 1) ? m[rr] : qd[rr];
          union { f16x2 h; unsigned u; } P; P.h = f16x2{(f16)ve, (f16)vo};
          hS32[row * 260 + cp] = P.u;
        }
      }
      __syncthreads();
    }
    // ---- final: out[row0..row0+16] = h2 @ w_out^T + b_out ----
    {
      const int rl = wid * 2 + (lane >> 5);       // local row 0..15
      const int l32 = lane & 31;
      const f16* hr = &hS[rl * 520 + l32 * 16];
      f16x8 h0 = *(const f16x8*)hr;
      f16x8 h1v = *(const f16x8*)(hr + 8);
      float hf[16];
      #pragma unroll
      for (int j = 0; j < 8; ++j) { hf[j] = (float)h0[j]; hf[8 + j] = (float)h1v[j]; }
      #pragma unroll
      for (int c = 0; c < Cc; ++c) {
        const float* wr_ = w_out + (size_t)c * Hh + l32 * 16;
        float s = 0.f;
        #pragma unroll
        for (int j4 = 0; j4 < 4; ++j4) {
          float4 w4 = *(const float4*)(wr_ + j4 * 4);
          s += hf[j4*4]*w4.x + hf[j4*4+1]*w4.y + hf[j4*4+2]*w4.z + hf[j4*4+3]*w4.w;
        }
        #pragma unroll
        for (int off = 16; off >= 1; off >>= 1) s += __shfl_xor(s, off, 64);
        if (l32 == 0) out[(row0 + rl) * Cc + c] = s + b_out[c];
      }
    }
  }
}

extern "C" void kernel_launch(void* const* d_in, const int* in_sizes, int n_in,
                              void* d_out, int out_size, void* d_ws, size_t ws_size,
                              hipStream_t stream) {
  (void)in_sizes; (void)n_in; (void)out_size; (void)ws_size;
  const float* x     = (const float*)d_in[0];
  const float* w_ih1 = (const float*)d_in[1];
  const float* w_hh1 = (const float*)d_in[2];
  const float* b_ih1 = (const float*)d_in[3];
  const float* b_hh1 = (const float*)d_in[4];
  const float* w_ih2 = (const float*)d_in[5];
  const float* w_hh2 = (const float*)d_in[6];
  const float* b_ih2 = (const float*)d_in[7];
  const float* b_hh2 = (const float*)d_in[8];
  const float* w_out = (const float*)d_in[9];
  const float* b_out = (const float*)d_in[10];
  float* out = (float*)d_out;
  char* ws = (char*)d_ws;

  hipMemsetAsync(ws, 0, 4096, stream);  // flags only

  hipLaunchKernelGGL(prep_weights, dim3(1024), dim3(256), 0, stream,
                     w_ih1, w_hh1, w_ih2, w_hh2, b_ih1, b_hh1, b_ih2, b_hh2, ws);

  hipLaunchKernelGGL(rnn_pipeline, dim3(32), dim3(512), 0, stream,
                     x, w_out, b_out, out, ws);
}

// Round 7
// 7352.872 us; speedup vs baseline: 2.2349x; 2.1858x over previous
//
#include <hip/hip_runtime.h>
#include <hip/hip_fp16.h>

#define Tt 1024
#define Ii 256
#define Hh 512
#define Cc 10
#define SPINMAX (1 << 27)

typedef _Float16 f16;
typedef _Float16 f16x8 __attribute__((ext_vector_type(8)));
typedef _Float16 f16x4 __attribute__((ext_vector_type(4)));
typedef _Float16 f16x2 __attribute__((ext_vector_type(2)));
typedef float    f32x4 __attribute__((ext_vector_type(4)));

// ---- ws byte offsets ----
#define OFF_FLAGS 0u        // ints: f_h1[8]@0, f_h2[8]@16, f_xw[8][2][2]@32, f_2a[8][3][4]@96
#define OFF_WH1   4096u     // f16 [512][512] w_hh1
#define OFF_WH2   528384u   // f16 [512][512] w_hh2
#define OFF_XWR   1052672u  // f16 [16 slot][8 bg][8192] frag-major (2 MB)
#define OFF_H1R   3149824u  // f16 [8 slot][8 bg][16*512] row-major (1 MB)
#define OFF_PAR   4198400u  // f16 [8 slot][8 bg][8192] frag-major (1 MB)

static __device__ __forceinline__ f32x4 mfma16(f16x8 a, f16x8 b, f32x4 c) {
  return __builtin_amdgcn_mfma_f32_16x16x32_f16(a, b, c, 0, 0, 0);
}
static __device__ __forceinline__ float fast_tanh(float v) {
  float e = __expf(2.0f * v);
  return 1.0f - 2.0f / (e + 1.0f);
}
static __device__ __forceinline__ int ldflag(const int* p) {
  return __hip_atomic_load(p, __ATOMIC_RELAXED, __HIP_MEMORY_SCOPE_AGENT);
}
static __device__ __forceinline__ void stflag(int* p, int v) {
  __hip_atomic_store(p, v, __ATOMIC_RELAXED, __HIP_MEMORY_SCOPE_AGENT);
}
static __device__ __forceinline__ f16x4 ld64cc(const f16* p) {
  union { unsigned long long u; f16x4 v; } U;
  U.u = __hip_atomic_load((const unsigned long long*)p, __ATOMIC_RELAXED, __HIP_MEMORY_SCOPE_AGENT);
  return U.v;
}
static __device__ __forceinline__ void st64cc(f16* p, f16x4 v) {
  union { unsigned long long u; f16x4 v; } U; U.v = v;
  __hip_atomic_store((unsigned long long*)p, U.u, __ATOMIC_RELAXED, __HIP_MEMORY_SCOPE_AGENT);
}
static __device__ __forceinline__ f16x8 ld128cc(const f16* p) {
  union { unsigned long long u[2]; f16x8 v; } U;
  U.u[0] = __hip_atomic_load((const unsigned long long*)p,     __ATOMIC_RELAXED, __HIP_MEMORY_SCOPE_AGENT);
  U.u[1] = __hip_atomic_load((const unsigned long long*)p + 1, __ATOMIC_RELAXED, __HIP_MEMORY_SCOPE_AGENT);
  return U.v;
}
static __device__ __forceinline__ void stu32cc(unsigned* p, unsigned v) {
  __hip_atomic_store(p, v, __ATOMIC_RELAXED, __HIP_MEMORY_SCOPE_AGENT);
}
static __device__ __forceinline__ int imin(int a, int b) { return a < b ? a : b; }

#define CFENCE() asm volatile("" ::: "memory")
#define VMFENCE() asm volatile("s_waitcnt vmcnt(0)" ::: "memory")
#define LBAR() do { asm volatile("s_waitcnt lgkmcnt(0)" ::: "memory"); \
                    __builtin_amdgcn_s_barrier(); \
                    __builtin_amdgcn_sched_barrier(0); } while (0)

// ---------- prologue kernel: w_hh1/w_hh2 fp32 -> f16 row-major ----------
__global__ void prep_weights(const float* __restrict__ w_hh1,
                             const float* __restrict__ w_hh2,
                             char* __restrict__ ws) {
  f16* wh1 = (f16*)(ws + OFF_WH1);
  f16* wh2 = (f16*)(ws + OFF_WH2);
  int i = blockIdx.x * 512 + threadIdx.x;
  if (i < 512 * 512) { wh1[i] = (f16)w_hh1[i]; wh2[i] = (f16)w_hh2[i]; }
}

// ---------- main persistent kernel ----------
__global__ __launch_bounds__(512, 1) void rnn_main(
    const float* __restrict__ x,
    const float* __restrict__ w_ih1, const float* __restrict__ w_ih2,
    const float* __restrict__ b_ih1, const float* __restrict__ b_hh1,
    const float* __restrict__ b_ih2, const float* __restrict__ b_hh2,
    const float* __restrict__ w_out, const float* __restrict__ b_out,
    float* __restrict__ out, char* __restrict__ ws)
{
  __shared__ __align__(16) char LS[147712];

  int* FL = (int*)(ws + OFF_FLAGS);
  const f16* wh1f = (const f16*)(ws + OFF_WH1);
  const f16* wh2f = (const f16*)(ws + OFF_WH2);
  f16* xwr = (f16*)(ws + OFF_XWR);
  f16* h1r = (f16*)(ws + OFF_H1R);
  f16* parr = (f16*)(ws + OFF_PAR);

  const int bid  = blockIdx.x;
  const int tid  = threadIdx.x;
  const int wid  = tid >> 6;
  const int lane = tid & 63;
  const int lm   = lane & 15;
  const int lgrp = lane >> 4;
  const int lk8  = lgrp * 8;
  const int rlo  = (lane & 1) * 2;

  if (bid < 16) {
    // ================== H1 (bid 0..7) / H2 (bid 8..15) ==================
    const bool isH1 = (bid < 8);
    const int bg = bid & 7;
    f16* sB = (f16*)LS;                 // [4 kc][4 grp][512 col][8] = 128 KB
    f16* sH = (f16*)(LS + 131072);      // [16][520] state
    unsigned* sH32 = (unsigned*)sH;
    const f16* whh = isH1 ? wh1f : wh2f;
    const int wcol0 = wid * 64;

    // stage sB: kc 0..3 of whh, frag layout
    for (int i = tid; i < 8192; i += 512) {
      const int kc = i >> 11, grp = (i >> 9) & 3, col = i & 511;
      f16x8 v = *(const f16x8*)&whh[col * 512 + kc * 32 + grp * 8];
      *(f16x8*)&sB[(size_t)i * 8] = v;
    }
    for (int i = tid; i < 16 * 260; i += 512) sH32[i] = 0u;
    // reg-B: kc 4..15
    f16x8 wb[12][4];
    #pragma unroll
    for (int kr = 0; kr < 12; ++kr)
      #pragma unroll
      for (int nt = 0; nt < 4; ++nt)
        wb[kr][nt] = *(const f16x8*)&whh[(size_t)(wcol0 + nt * 16 + lm) * 512 + (kr + 4) * 32 + lk8];
    __syncthreads();

    int fA_cur = -1;   // H1: min xw-pair; H2: min 2a-quad for current step
    int fG_cur = -1;   // H1: min 2a-quad (ring guard); H2: unused
    const int T = Tt;

    for (int p = 0; p < T; ++p) {
      // ---- 1. flag checks (prefetched; spin with bail only if behind) ----
      if (isH1) {
        if (fA_cur < p + 1) {
          const int* pa = FL + 32 + (bg * 2 + (p & 1)) * 2;
          int s = 0, a, b;
          do { a = ldflag(pa); b = ldflag(pa + 1); if (++s > SPINMAX) break; }
          while (imin(a, b) < p + 1);
        }
        if (p >= 8 && fG_cur < p - 7) {
          const int sg = (p - 8) % 3;
          const int* qa = FL + 96 + (bg * 3 + sg) * 4;
          int s = 0, m;
          do { m = imin(imin(ldflag(qa), ldflag(qa + 1)), imin(ldflag(qa + 2), ldflag(qa + 3)));
               if (++s > SPINMAX) break; } while (m < p - 7);
        }
      } else {
        if (fA_cur < p + 1) {
          const int sg = p % 3;
          const int* qa = FL + 96 + (bg * 3 + sg) * 4;
          int s = 0, m;
          do { m = imin(imin(ldflag(qa), ldflag(qa + 1)), imin(ldflag(qa + 2), ldflag(qa + 3)));
               if (++s > SPINMAX) break; } while (m < p + 1);
        }
      }
      CFENCE();

      // ---- 2. issue feed-in loads (xw_p or par_p), frag-major ----
      const f16* fin = isH1 ? (xwr + ((size_t)(p & 15) * 8 + bg) * 8192)
                            : (parr + ((size_t)(p & 7) * 8 + bg) * 8192);
      f16x4 xv[4];
      #pragma unroll
      for (int nt = 0; nt < 4; ++nt)
        xv[nt] = ld64cc(fin + (wid * 4 + nt) * 256 + lm * 16 + lgrp * 4);

      // ---- 3. MFMA phase (state part; reads sH = h_{p-1}) ----
      f32x4 acc[4];
      #pragma unroll
      for (int nt = 0; nt < 4; ++nt) acc[nt] = f32x4{0.f, 0.f, 0.f, 0.f};
      if (p > 0) {
        #pragma unroll
        for (int kc = 0; kc < 16; ++kc) {
          f16x8 A = *(const f16x8*)&sH[lm * 520 + kc * 32 + lk8];
          if (kc < 4) {
            #pragma unroll
            for (int nt = 0; nt < 4; ++nt)
              acc[nt] = mfma16(A, *(const f16x8*)&sB[((size_t)(kc * 4 + lgrp) * 512 + wcol0 + nt * 16 + lm) * 8], acc[nt]);
          } else {
            #pragma unroll
            for (int nt = 0; nt < 4; ++nt)
              acc[nt] = mfma16(A, wb[kc - 4][nt], acc[nt]);
          }
        }
      }
      // barrier A: all state reads done before state overwrite
      LBAR();

      // ---- 4. add feed-in ----
      #pragma unroll
      for (int nt = 0; nt < 4; ++nt) {
        #pragma unroll
        for (int r = 0; r < 4; ++r) acc[nt][r] += (float)xv[nt][r];
      }

      // ---- 5. periodic publish (stores of step p-1 are a period old: drain ~free) ----
      if ((p & 3) == 0 && p > 0) {
        VMFENCE();
        if (tid == 0) stflag(FL + (isH1 ? 0 : 16) + bg, p);
      }

      // ---- 6. tanh + epi: write sH (ds) and (H1 only) h1 ring (sc1) ----
      unsigned* ring32 = (unsigned*)(h1r + ((size_t)(p & 7) * 8 + bg) * 8192);
      #pragma unroll
      for (int nt = 0; nt < 4; ++nt) {
        const int cp = (wcol0 + nt * 16 + lm) >> 1;
        float v0 = fast_tanh(acc[nt][0]), v1 = fast_tanh(acc[nt][1]);
        float v2 = fast_tanh(acc[nt][2]), v3 = fast_tanh(acc[nt][3]);
        float o0 = __shfl_xor(v0, 1, 64), o1 = __shfl_xor(v1, 1, 64);
        float o2 = __shfl_xor(v2, 1, 64), o3 = __shfl_xor(v3, 1, 64);
        float m[4] = {v0, v1, v2, v3}, q[4] = {o0, o1, o2, o3};
        #pragma unroll
        for (int r2 = 0; r2 < 2; ++r2) {
          const int rr = rlo + r2, row = lgrp * 4 + rr;
          float ve = (lane & 1) ? q[rr] : m[rr];
          float vo = (lane & 1) ? m[rr] : q[rr];
          union { f16x2 h; unsigned u; } P; P.h = f16x2{(f16)ve, (f16)vo};
          sH32[row * 260 + cp] = P.u;
          if (isH1) stu32cc(ring32 + row * 256 + cp, P.u);
        }
      }

      // ---- 7. prefetch flags for p+1 (consumed next iteration) ----
      if (isH1) {
        const int* pa = FL + 32 + (bg * 2 + ((p + 1) & 1)) * 2;
        fA_cur = imin(ldflag(pa), ldflag(pa + 1));
        const int sg2 = (p + 1 >= 8) ? ((p - 7) % 3) : 0;
        const int* qa = FL + 96 + (bg * 3 + sg2) * 4;
        fG_cur = imin(imin(ldflag(qa), ldflag(qa + 1)), imin(ldflag(qa + 2), ldflag(qa + 3)));
      } else {
        const int sg2 = (p + 1) % 3;
        const int* qa = FL + 96 + (bg * 3 + sg2) * 4;
        fA_cur = imin(imin(ldflag(qa), ldflag(qa + 1)), imin(ldflag(qa + 2), ldflag(qa + 3)));
      }

      // barrier B: state writes visible before next step's reads
      LBAR();
    }

    // final publish
    VMFENCE();
    if (tid == 0) stflag(FL + (isH1 ? 0 : 16) + bg, Tt);
    if (tid == 0 && isH1) stflag(FL + bg, Tt + 1);   // generous terminal value
    if (tid == 0 && !isH1) stflag(FL + 16 + bg, Tt + 1);

    // ---- H2: final output  out = h2_{T-1} @ w_out^T + b_out ----
    if (!isH1) {
      const int rl = wid * 2 + (lane >> 5);
      const int l32 = lane & 31;
      const f16* hr = &sH[rl * 520 + l32 * 16];
      f16x8 h0 = *(const f16x8*)hr;
      f16x8 h1v = *(const f16x8*)(hr + 8);
      float hf[16];
      #pragma unroll
      for (int j = 0; j < 8; ++j) { hf[j] = (float)h0[j]; hf[8 + j] = (float)h1v[j]; }
      #pragma unroll
      for (int c = 0; c < Cc; ++c) {
        const float* wr_ = w_out + (size_t)c * Hh + l32 * 16;
        float s = 0.f;
        #pragma unroll
        for (int j4 = 0; j4 < 4; ++j4) {
          float4 w4 = *(const float4*)(wr_ + j4 * 4);
          s += hf[j4*4]*w4.x + hf[j4*4+1]*w4.y + hf[j4*4+2]*w4.z + hf[j4*4+3]*w4.w;
        }
        #pragma unroll
        for (int off = 16; off >= 1; off >>= 1) s += __shfl_xor(s, off, 64);
        if (l32 == 0) out[(bg * 16 + rl) * Cc + c] = s + b_out[c];
      }
    }
  } else if (bid < 112) {
    // ================== 2A (bid 16..111): par = h1 @ w_ih2^T + b2 ==================
    const int idx = bid - 16;
    const int bg = idx / 12, r = idx % 12;
    const int set = r >> 2, cb = r & 3;
    f16* sW = (f16*)LS;                 // [16 kc][4 grp][128 col][8] = 128 KB
    f16* sA = (f16*)(LS + 131072);      // staged h1 [16][520]

    for (int i = tid; i < 8192; i += 512) {
      const int kc = i >> 9, grp = (i >> 7) & 3, cl = i & 127;
      const float* sp = w_ih2 + (size_t)(cb * 128 + cl) * 512 + kc * 32 + grp * 8;
      float4 a = *(const float4*)sp, b = *(const float4*)(sp + 4);
      f16x8 v{(f16)a.x,(f16)a.y,(f16)a.z,(f16)a.w,(f16)b.x,(f16)b.y,(f16)b.z,(f16)b.w};
      *(f16x8*)&sW[(size_t)i * 8] = v;
    }
    const int gcol = cb * 128 + wid * 16 + lm;
    const float bias2v = b_ih2[gcol] + b_hh2[gcol];
    __syncthreads();

    for (int q = set; q < Tt; q += 3) {
      if (q >= 8) {             // par ring overwrite guard
        int s = 0;
        while (ldflag(FL + 16 + bg) < q - 7) { if (++s > SPINMAX) break; __builtin_amdgcn_s_sleep(1); }
      }
      { int s = 0;              // wait h1_q visible
        while (ldflag(FL + bg) < q + 1) { if (++s > SPINMAX) break; __builtin_amdgcn_s_sleep(1); } }
      CFENCE();
      // stage h1_q slice into LDS (padded rows)
      const f16* hsrc = h1r + ((size_t)(q & 7) * 8 + bg) * 8192;
      #pragma unroll
      for (int c = 0; c < 2; ++c) {
        const int ch = tid * 2 + c;
        const int row = ch >> 6, c16 = ch & 63;
        f16x8 v = ld128cc(hsrc + ch * 8);
        *(f16x8*)&sA[row * 520 + c16 * 8] = v;
      }
      __syncthreads();
      f32x4 acc = {bias2v, bias2v, bias2v, bias2v};
      #pragma unroll
      for (int kc = 0; kc < 16; ++kc) {
        f16x8 A = *(const f16x8*)&sA[lm * 520 + kc * 32 + lk8];
        f16x8 B = *(const f16x8*)&sW[((size_t)(kc * 4 + lgrp) * 128 + wid * 16 + lm) * 8];
        acc = mfma16(A, B, acc);
      }
      f16x4 pv{(f16)acc[0], (f16)acc[1], (f16)acc[2], (f16)acc[3]};
      st64cc(parr + ((size_t)(q & 7) * 8 + bg) * 8192 + (cb * 8 + wid) * 256 + lm * 16 + lgrp * 4, pv);
      VMFENCE();
      if (tid == 0) stflag(FL + 96 + (bg * 3 + set) * 4 + cb, q + 1);
      __syncthreads();
    }
  } else {
    // ================== XW (bid 112..143): xw = x_t @ w_ih1^T + b1 ==================
    const int idx = bid - 112;
    const int bg = idx >> 2, r = idx & 3;
    const int set = r >> 1, half = r & 1;
    f16* sW = (f16*)LS;                 // [8 kc][4 grp][256 col][8] = 128 KB

    for (int i = tid; i < 8192; i += 512) {
      const int kc = i >> 10, grp = (i >> 8) & 3, cl = i & 255;
      const float* sp = w_ih1 + (size_t)(half * 256 + cl) * 256 + kc * 32 + grp * 8;
      float4 a = *(const float4*)sp, b = *(const float4*)(sp + 4);
      f16x8 v{(f16)a.x,(f16)a.y,(f16)a.z,(f16)a.w,(f16)b.x,(f16)b.y,(f16)b.z,(f16)b.w};
      *(f16x8*)&sW[(size_t)i * 8] = v;
    }
    const int gc0 = half * 256 + wid * 32 + lm;
    const float b1v0 = b_ih1[gc0] + b_hh1[gc0];
    const float b1v1 = b_ih1[gc0 + 16] + b_hh1[gc0 + 16];
    __syncthreads();

    for (int t = set; t < Tt; t += 2) {
      if (t >= 16) {            // xw ring overwrite guard
        int s = 0;
        while (ldflag(FL + bg) < t - 15) { if (++s > SPINMAX) break; __builtin_amdgcn_s_sleep(1); }
      }
      CFENCE();
      f32x4 acc0 = {b1v0, b1v0, b1v0, b1v0};
      f32x4 acc1 = {b1v1, b1v1, b1v1, b1v1};
      const float* xr = x + ((size_t)(bg * 16 + lm) * Tt + t) * Ii + lk8;
      #pragma unroll
      for (int kc = 0; kc < 8; ++kc) {
        float4 a = *(const float4*)(xr + kc * 32);
        float4 b = *(const float4*)(xr + kc * 32 + 4);
        f16x8 A{(f16)a.x,(f16)a.y,(f16)a.z,(f16)a.w,(f16)b.x,(f16)b.y,(f16)b.z,(f16)b.w};
        acc0 = mfma16(A, *(const f16x8*)&sW[((size_t)(kc * 4 + lgrp) * 256 + wid * 32 + lm) * 8], acc0);
        acc1 = mfma16(A, *(const f16x8*)&sW[((size_t)(kc * 4 + lgrp) * 256 + wid * 32 + 16 + lm) * 8], acc1);
      }
      f16* dst = xwr + ((size_t)(t & 15) * 8 + bg) * 8192;
      f16x4 p0{(f16)acc0[0], (f16)acc0[1], (f16)acc0[2], (f16)acc0[3]};
      f16x4 p1{(f16)acc1[0], (f16)acc1[1], (f16)acc1[2], (f16)acc1[3]};
      st64cc(dst + (half * 16 + wid * 2 + 0) * 256 + lm * 16 + lgrp * 4, p0);
      st64cc(dst + (half * 16 + wid * 2 + 1) * 256 + lm * 16 + lgrp * 4, p1);
      VMFENCE();
      if (tid == 0) stflag(FL + 32 + (bg * 2 + set) * 2 + half, t + 1);
    }
  }
}

extern "C" void kernel_launch(void* const* d_in, const int* in_sizes, int n_in,
                              void* d_out, int out_size, void* d_ws, size_t ws_size,
                              hipStream_t stream) {
  (void)in_sizes; (void)n_in; (void)out_size; (void)ws_size;
  const float* x     = (const float*)d_in[0];
  const float* w_ih1 = (const float*)d_in[1];
  const float* w_hh1 = (const float*)d_in[2];
  const float* b_ih1 = (const float*)d_in[3];
  const float* b_hh1 = (const float*)d_in[4];
  const float* w_ih2 = (const float*)d_in[5];
  const float* w_hh2 = (const float*)d_in[6];
  const float* b_ih2 = (const float*)d_in[7];
  const float* b_hh2 = (const float*)d_in[8];
  const float* w_out = (const float*)d_in[9];
  const float* b_out = (const float*)d_in[10];
  float* out = (float*)d_out;
  char* ws = (char*)d_ws;

  hipMemsetAsync(ws, 0, 4096, stream);   // flags
  hipLaunchKernelGGL(prep_weights, dim3(512), dim3(512), 0, stream, w_hh1, w_hh2, ws);
  hipLaunchKernelGGL(rnn_main, dim3(144), dim3(512), 0, stream,
                     x, w_ih1, w_ih2, b_ih1, b_hh1, b_ih2, b_hh2,
                     w_out, b_out, out, ws);
}